// Round 8
// baseline (318.780 us; speedup 1.0000x reference)
//
#include <hip/hip_runtime.h>
#include <math.h>

#define IN_FEATS 128
#define HIDDEN   256
#define CLASSES  41
#define CPAD     64
#define SCAN_BLK 1024
#define LDA      264   // 256 + 8 pad (bf16 elems)
#define EK       8     // edges per thread in fill
#define NSH      8     // histogram shards

typedef __attribute__((ext_vector_type(8))) short short8;
typedef __attribute__((ext_vector_type(4))) float f32x4;

__device__ __forceinline__ unsigned short f2bf(float f) {
    union { float f; unsigned u; } v; v.f = f;
    unsigned r = v.u + 0x7FFF + ((v.u >> 16) & 1);
    return (unsigned short)(r >> 16);
}
__device__ __forceinline__ float bf2f(unsigned short h) {
    union { unsigned u; float f; } v; v.u = ((unsigned)h) << 16;
    return v.f;
}

// ---- fused prepass: hist (sharded) + xbf + prep, role-interleaved ----------
// role = blockIdx%3: 0 -> hist block q; 1,2 -> aux block a = q*2+(r-1)
__global__ void __launch_bounds__(256)
prepass_kernel(const int* __restrict__ dst, int* __restrict__ deg_sh,
               unsigned short* __restrict__ rank, int E, int HB,
               const float* __restrict__ x, unsigned short* __restrict__ xbf,
               long n4, int XB,
               const float* __restrict__ W1l, const float* __restrict__ W1r,
               const float* __restrict__ W2l, const float* __restrict__ W2r,
               unsigned short* __restrict__ Bp1, unsigned short* __restrict__ Bp2,
               int N) {
    int b = blockIdx.x;
    int r = b % 3, q = b / 3;
    int t = threadIdx.x;
    if (r == 0) {
        // ---- hist role: rank[e] = deg_sh[shard][dst[e]]++ ----
        if (q >= HB) return;
        int e = q * 256 + t;
        if (e < E) {
            int d = dst[e];
            int sh = q & (NSH - 1);
            rank[e] = (unsigned short)atomicAdd(&deg_sh[(size_t)sh * N + d], 1);
        }
        return;
    }
    int a = q * 2 + (r - 1);
    if (a < XB) {
        // ---- xbf role ----
        long i = (long)a * 256 + t;
        if (i < n4) {
            float4 v = *(const float4*)(x + i * 4);
            ushort4 o;
            o.x = f2bf(v.x); o.y = f2bf(v.y); o.z = f2bf(v.z); o.w = f2bf(v.w);
            *(ushort4*)(xbf + i * 4) = o;
        }
        return;
    }
    // ---- prep role ----
    int idx = (a - XB) * 256 + t;
    if (idx < 256 * 256) {
        int k = idx >> 8, c = idx & 255;
        float v = (k < 128) ? W1l[k * 256 + c] : W1r[(k - 128) * 256 + c];
        Bp1[((k >> 5) * 256 + c) * 32 + ((k & 31) >> 3) * 8 + (k & 7)] = f2bf(v);
    } else {
        int j = idx - 65536;
        if (j < 256 * 96) {
            int k = j / 96, c = j % 96;
            float v = 0.0f;
            if (c < 41) v = W2l[k * 41 + c];
            else if (c >= 48 && c < 89) v = W2r[k * 41 + (c - 48)];
            Bp2[((k >> 5) * 96 + c) * 32 + ((k & 31) >> 3) * 8 + (k & 7)] = f2bf(v);
        }
    }
}

// ---- scan1: sum 8 shards, exclusive scan; emit row_start (+sentinel) + rss --
__global__ void __launch_bounds__(256)
scan1_kernel(const int* __restrict__ deg_sh, int* __restrict__ row_start,
             int* __restrict__ rss, int* __restrict__ blk_sums, int N) {
    __shared__ int lds[256];
    int base = blockIdx.x * SCAN_BLK;
    int t = threadIdx.x;
    int d8[4][8];
    int v[4];
    int s = 0;
#pragma unroll
    for (int i = 0; i < 4; ++i) {
        int idx = base + t * 4 + i;
        int tot = 0;
#pragma unroll
        for (int sh = 0; sh < NSH; ++sh) {
            int dv = (idx < N) ? deg_sh[(size_t)sh * N + idx] : 0;
            d8[i][sh] = dv;
            tot += dv;
        }
        v[i] = tot;
        s += tot;
    }
    lds[t] = s;
    __syncthreads();
    for (int off = 1; off < 256; off <<= 1) {
        int val = lds[t];
        int add = (t >= off) ? lds[t - off] : 0;
        __syncthreads();
        lds[t] = val + add;
        __syncthreads();
    }
    if (t == 255) blk_sums[blockIdx.x] = lds[255];
    int run = (t == 0) ? 0 : lds[t - 1];
#pragma unroll
    for (int i = 0; i < 4; ++i) {
        int idx = base + t * 4 + i;
        if (idx <= N) row_start[idx] = run;
        int acc = run;
#pragma unroll
        for (int sh = 0; sh < NSH; ++sh) {
            if (idx < N) rss[(size_t)sh * N + idx] = acc;
            acc += d8[i][sh];
        }
        run = acc;
    }
}

__global__ void __launch_bounds__(256)
scan2_kernel(int* __restrict__ blk_sums, int nb) {
    __shared__ int lds[256];
    int t = threadIdx.x;
    lds[t] = (t < nb) ? blk_sums[t] : 0;
    __syncthreads();
    for (int off = 1; off < 256; off <<= 1) {
        int val = lds[t];
        int add = (t >= off) ? lds[t - off] : 0;
        __syncthreads();
        lds[t] = val + add;
        __syncthreads();
    }
    if (t < nb) blk_sums[t] = (t == 0) ? 0 : lds[t - 1];
}

__global__ void __launch_bounds__(256)
scan3_kernel(int* __restrict__ row_start, int* __restrict__ rss,
             const int* __restrict__ blk_sums, int N) {
    int idx = blockIdx.x * blockDim.x + threadIdx.x;
    if (idx > N) return;
    int add = blk_sums[idx / SCAN_BLK];
    row_start[idx] += add;
    if (idx < N) {
#pragma unroll
        for (int sh = 0; sh < NSH; ++sh) rss[(size_t)sh * N + idx] += add;
    }
}

// ------ fill: csr_src[rss[shard(e)][dst[e]] + rank[e]] = src[e] -------------
__global__ void __launch_bounds__(256)
fill_kernel(const int* __restrict__ src, const int* __restrict__ dst,
            const int* __restrict__ rss, const unsigned short* __restrict__ rank,
            int* __restrict__ csr_src, int E, int T, int N) {
    int tid = blockIdx.x * 256 + threadIdx.x;
    int d[EK], s[EK], rk[EK], sh[EK];
#pragma unroll
    for (int j = 0; j < EK; ++j) {
        int e = tid + j * T;
        if (e < E) {
            d[j] = dst[e]; s[j] = src[e]; rk[j] = rank[e];
            sh[j] = (e >> 8) & (NSH - 1);
        } else { d[j] = -1; s[j] = 0; rk[j] = 0; sh[j] = 0; }
    }
    int rs[EK];
#pragma unroll
    for (int j = 0; j < EK; ++j)
        rs[j] = (d[j] >= 0) ? rss[(size_t)sh[j] * N + d[j]] : 0;
#pragma unroll
    for (int j = 0; j < EK; ++j)
        if (d[j] >= 0) csr_src[rs[j] + rk[j]] = s[j];
}

// ------- gather1: aggm_bf[n] = bf16(mean_{s} xbf[s]), unroll-8 MLP ----------
__global__ void __launch_bounds__(256)
gather1_kernel(const unsigned short* __restrict__ xbf,
               const int* __restrict__ row_start,
               const int* __restrict__ csr_src, unsigned short* __restrict__ aggm,
               int N) {
    int wid = (blockIdx.x * 256 + threadIdx.x) >> 6;
    int lane = threadIdx.x & 63;
    if (wid >= N) return;
    int rs = row_start[wid];
    int d = row_start[wid + 1] - rs;
    const unsigned* xp = (const unsigned*)xbf;
    float sl[8], sh[8];
#pragma unroll
    for (int j = 0; j < 8; ++j) { sl[j] = 0.f; sh[j] = 0.f; }
    int i = 0;
    for (; i + 8 <= d; i += 8) {
        int s[8];
#pragma unroll
        for (int j = 0; j < 8; ++j) s[j] = csr_src[rs + i + j];
        unsigned u[8];
#pragma unroll
        for (int j = 0; j < 8; ++j) u[j] = xp[(size_t)s[j] * 64 + lane];
#pragma unroll
        for (int j = 0; j < 8; ++j) {
            sl[j] += bf2f((unsigned short)u[j]);
            sh[j] += bf2f((unsigned short)(u[j] >> 16));
        }
    }
    for (; i + 4 <= d; i += 4) {
        int s[4];
#pragma unroll
        for (int j = 0; j < 4; ++j) s[j] = csr_src[rs + i + j];
        unsigned u[4];
#pragma unroll
        for (int j = 0; j < 4; ++j) u[j] = xp[(size_t)s[j] * 64 + lane];
#pragma unroll
        for (int j = 0; j < 4; ++j) {
            sl[j] += bf2f((unsigned short)u[j]);
            sh[j] += bf2f((unsigned short)(u[j] >> 16));
        }
    }
    for (; i < d; ++i) {
        unsigned u0 = xp[(size_t)csr_src[rs + i] * 64 + lane];
        sl[0] += bf2f((unsigned short)u0);
        sh[0] += bf2f((unsigned short)(u0 >> 16));
    }
    float ax = ((sl[0] + sl[1]) + (sl[2] + sl[3])) + ((sl[4] + sl[5]) + (sl[6] + sl[7]));
    float ay = ((sh[0] + sh[1]) + (sh[2] + sh[3])) + ((sh[4] + sh[5]) + (sh[6] + sh[7]));
    float inv = 1.0f / fmaxf((float)d, 1.0f);
    unsigned o = ((unsigned)f2bf(ay * inv) << 16) | (unsigned)f2bf(ax * inv);
    ((unsigned*)aggm)[(size_t)wid * 64 + lane] = o;
}

// ------- mgemm1: h1 = bf16(relu([aggm|xbf] @ Bp1 + b1)), MFMA ---------------
__global__ void __launch_bounds__(256)
mgemm1_kernel(const unsigned short* __restrict__ aggm,
              const unsigned short* __restrict__ xbf,
              const unsigned short* __restrict__ Bp1, const float* __restrict__ b1,
              unsigned short* __restrict__ h1, int N) {
    __shared__ __align__(16) unsigned short alds[64 * LDA];
    int n0 = blockIdx.x * 64;
    int t = threadIdx.x;
#pragma unroll
    for (int i = 0; i < 8; ++i) {
        int cid = t + i * 256;
        int row = cid >> 5, c16 = cid & 31;
        int gr = n0 + row;
        uint4 v = make_uint4(0, 0, 0, 0);
        if (gr < N) {
            const unsigned short* srcp = (c16 < 16)
                ? (aggm + (size_t)gr * 128 + c16 * 8)
                : (xbf  + (size_t)gr * 128 + (c16 - 16) * 8);
            v = *(const uint4*)srcp;
        }
        *(uint4*)&alds[row * LDA + c16 * 8] = v;
    }
    __syncthreads();
    int wid = t >> 6, lane = t & 63;
    int l15 = lane & 15, g = lane >> 4;
    int col0 = wid * 64;
    f32x4 acc[4][4];
#pragma unroll
    for (int mf = 0; mf < 4; ++mf)
#pragma unroll
        for (int nf = 0; nf < 4; ++nf) acc[mf][nf] = (f32x4)(0.0f);
    for (int ks = 0; ks < 8; ++ks) {
        short8 af[4], bfr[4];
#pragma unroll
        for (int mf = 0; mf < 4; ++mf)
            af[mf] = *(const short8*)&alds[(mf * 16 + l15) * LDA + ks * 32 + g * 8];
#pragma unroll
        for (int nf = 0; nf < 4; ++nf)
            bfr[nf] = *(const short8*)&Bp1[((size_t)ks * 256 + col0 + nf * 16 + l15) * 32 + g * 8];
#pragma unroll
        for (int mf = 0; mf < 4; ++mf)
#pragma unroll
            for (int nf = 0; nf < 4; ++nf)
                acc[mf][nf] = __builtin_amdgcn_mfma_f32_16x16x32_bf16(
                    af[mf], bfr[nf], acc[mf][nf], 0, 0, 0);
    }
    float bc[4];
#pragma unroll
    for (int nf = 0; nf < 4; ++nf) bc[nf] = b1[col0 + nf * 16 + l15];
#pragma unroll
    for (int mf = 0; mf < 4; ++mf) {
        int rowb = n0 + mf * 16 + g * 4;
#pragma unroll
        for (int r = 0; r < 4; ++r) {
            int row = rowb + r;
            if (row < N) {
#pragma unroll
                for (int nf = 0; nf < 4; ++nf)
                    h1[(size_t)row * 256 + col0 + nf * 16 + l15] =
                        f2bf(fmaxf(acc[mf][nf][r] + bc[nf], 0.0f));
            }
        }
    }
}

// ------- mgemm2: zb = bf16(h1@W2l) ; rbuf = h1@W2r + b2 ---------------------
__global__ void __launch_bounds__(256)
mgemm2_kernel(const unsigned short* __restrict__ h1,
              const unsigned short* __restrict__ Bp2, const float* __restrict__ b2,
              unsigned short* __restrict__ zb, float* __restrict__ rbuf, int N) {
    __shared__ __align__(16) unsigned short alds[64 * LDA];
    int n0 = blockIdx.x * 64;
    int t = threadIdx.x;
#pragma unroll
    for (int i = 0; i < 8; ++i) {
        int cid = t + i * 256;
        int row = cid >> 5, c16 = cid & 31;
        int gr = n0 + row;
        uint4 v = make_uint4(0, 0, 0, 0);
        if (gr < N) v = *(const uint4*)(h1 + (size_t)gr * 256 + c16 * 8);
        *(uint4*)&alds[row * LDA + c16 * 8] = v;
    }
    __syncthreads();
    int wid = t >> 6, lane = t & 63;
    int l15 = lane & 15, g = lane >> 4;
    int wr = wid >> 1, wc = wid & 1;
    f32x4 acc[2][3];
#pragma unroll
    for (int mf = 0; mf < 2; ++mf)
#pragma unroll
        for (int nf = 0; nf < 3; ++nf) acc[mf][nf] = (f32x4)(0.0f);
    for (int ks = 0; ks < 8; ++ks) {
        short8 af[2], bfr[3];
#pragma unroll
        for (int mf = 0; mf < 2; ++mf)
            af[mf] = *(const short8*)&alds[(wr * 32 + mf * 16 + l15) * LDA + ks * 32 + g * 8];
#pragma unroll
        for (int nf = 0; nf < 3; ++nf)
            bfr[nf] = *(const short8*)&Bp2[((size_t)ks * 96 + wc * 48 + nf * 16 + l15) * 32 + g * 8];
#pragma unroll
        for (int mf = 0; mf < 2; ++mf)
#pragma unroll
            for (int nf = 0; nf < 3; ++nf)
                acc[mf][nf] = __builtin_amdgcn_mfma_f32_16x16x32_bf16(
                    af[mf], bfr[nf], acc[mf][nf], 0, 0, 0);
    }
#pragma unroll
    for (int nf = 0; nf < 3; ++nf) {
        int col = wc * 48 + nf * 16 + l15;
        float bb = (col >= 48 && col < 89) ? b2[col - 48] : 0.0f;
#pragma unroll
        for (int mf = 0; mf < 2; ++mf) {
            int rowb = n0 + wr * 32 + mf * 16 + g * 4;
#pragma unroll
            for (int r = 0; r < 4; ++r) {
                int row = rowb + r;
                if (row < N) {
                    float v = acc[mf][nf][r];
                    if (col < 41)                   zb[(size_t)row * CPAD + col] = f2bf(v);
                    else if (col >= 48 && col < 89) rbuf[(size_t)row * CPAD + (col - 48)] = v + bb;
                }
            }
        }
    }
}

// -- gather2+final: 4 nodes/wave (16 lanes each, uint2 = 4 classes), unroll-4
__global__ void __launch_bounds__(256)
gather2_kernel(const uint2* __restrict__ zp, const float* __restrict__ rbuf,
               const int* __restrict__ row_start,
               const int* __restrict__ csr_src, float* __restrict__ out, int N) {
    int tid = blockIdx.x * 256 + threadIdx.x;
    int nid = tid >> 4;
    int l = tid & 15;
    if (nid >= N) return;
    int rs = row_start[nid];
    int d = row_start[nid + 1] - rs;
    float a[4][4];
#pragma unroll
    for (int j = 0; j < 4; ++j)
#pragma unroll
        for (int k = 0; k < 4; ++k) a[j][k] = 0.f;
    int i = 0;
    for (; i + 4 <= d; i += 4) {
        int s[4];
#pragma unroll
        for (int j = 0; j < 4; ++j) s[j] = csr_src[rs + i + j];
        uint2 u[4];
#pragma unroll
        for (int j = 0; j < 4; ++j) u[j] = zp[(size_t)s[j] * 16 + l];
#pragma unroll
        for (int j = 0; j < 4; ++j) {
            a[j][0] += bf2f((unsigned short)u[j].x);
            a[j][1] += bf2f((unsigned short)(u[j].x >> 16));
            a[j][2] += bf2f((unsigned short)u[j].y);
            a[j][3] += bf2f((unsigned short)(u[j].y >> 16));
        }
    }
    for (; i < d; ++i) {
        uint2 u0 = zp[(size_t)csr_src[rs + i] * 16 + l];
        a[0][0] += bf2f((unsigned short)u0.x);
        a[0][1] += bf2f((unsigned short)(u0.x >> 16));
        a[0][2] += bf2f((unsigned short)u0.y);
        a[0][3] += bf2f((unsigned short)(u0.y >> 16));
    }
    float inv = 1.0f / fmaxf((float)d, 1.0f);
    float4 rb = *(const float4*)&rbuf[(size_t)nid * CPAD + 4 * l];
    float rbv[4] = {rb.x, rb.y, rb.z, rb.w};
    float v[4];
#pragma unroll
    for (int k = 0; k < 4; ++k) {
        int col = 4 * l + k;
        v[k] = (col < CLASSES)
             ? ((a[0][k] + a[1][k]) + (a[2][k] + a[3][k])) * inv + rbv[k]
             : -INFINITY;
    }
    float m = fmaxf(fmaxf(v[0], v[1]), fmaxf(v[2], v[3]));
#pragma unroll
    for (int off = 8; off; off >>= 1) m = fmaxf(m, __shfl_xor(m, off, 16));
    float s = 0.f;
#pragma unroll
    for (int k = 0; k < 4; ++k)
        s += (4 * l + k < CLASSES) ? expf(v[k] - m) : 0.0f;
#pragma unroll
    for (int off = 8; off; off >>= 1) s += __shfl_xor(s, off, 16);
    float lse = m + logf(s);
#pragma unroll
    for (int k = 0; k < 4; ++k) {
        int col = 4 * l + k;
        if (col < CLASSES) out[(size_t)nid * CLASSES + col] = v[k] - lse;
    }
}

extern "C" void kernel_launch(void* const* d_in, const int* in_sizes, int n_in,
                              void* d_out, int out_size, void* d_ws, size_t ws_size,
                              hipStream_t stream) {
    const float* x   = (const float*)d_in[0];
    const int*   ei  = (const int*)d_in[1];
    const float* W1l = (const float*)d_in[2];
    const float* W1r = (const float*)d_in[3];
    const float* b1  = (const float*)d_in[4];
    const float* W2l = (const float*)d_in[5];
    const float* W2r = (const float*)d_in[6];
    const float* b2  = (const float*)d_in[7];
    float* out = (float*)d_out;

    int N = in_sizes[0] / IN_FEATS;
    int E = in_sizes[1] / 2;
    const int* src = ei;
    const int* dst = ei + E;

    // ints: [deg_sh 8N][blk_sums 256][row_start N+1][rss 8N][csr_src E], rank u16 E
    int* ws_i      = (int*)d_ws;
    int* deg_sh    = ws_i;
    int* blk_sums  = ws_i + (size_t)NSH * N;
    int* row_start = ws_i + (size_t)NSH * N + 256;
    int* rss       = row_start + (size_t)N + 1;
    int* csr_src   = rss + (size_t)NSH * N;
    unsigned short* rank = (unsigned short*)(csr_src + (size_t)E);
    size_t int_bytes = ((size_t)(2 * NSH + 1) * N + 257 + (size_t)E) * sizeof(int)
                     + (size_t)E * sizeof(unsigned short);
    char* p = (char*)d_ws + ((int_bytes + 15) & ~(size_t)15);
    unsigned short* xbf  = (unsigned short*)p;            p += (size_t)N * 128 * 2;
    unsigned short* aggm = (unsigned short*)p;            p += (size_t)N * 128 * 2;
    unsigned short* h1   = (unsigned short*)p;            p += (size_t)N * 256 * 2;
    unsigned short* Bp1  = (unsigned short*)p;            p += 65536 * 2;
    unsigned short* Bp2  = (unsigned short*)p;            p += 24576 * 2;
    unsigned short* zb   = (unsigned short*)p;            p += (size_t)N * CPAD * 2;
    float* rbuf = (float*)p;

    hipMemsetAsync(deg_sh, 0, ((size_t)NSH * N + 256) * sizeof(int), stream);

    // fused prepass: hist + xbf + prep
    long n4 = (long)N * 128 / 4;
    int HB = (E + 255) / 256;
    int XB = (int)((n4 + 255) / 256);
    int PB = (65536 + 24576) / 256;
    int M  = HB > (XB + PB + 1) / 2 ? HB : (XB + PB + 1) / 2;
    prepass_kernel<<<3 * M, 256, 0, stream>>>(dst, deg_sh, rank, E, HB,
                                              x, xbf, n4, XB,
                                              W1l, W1r, W2l, W2r, Bp1, Bp2, N);

    int nscan = (N + 1 + SCAN_BLK - 1) / SCAN_BLK;
    scan1_kernel<<<nscan, 256, 0, stream>>>(deg_sh, row_start, rss, blk_sums, N);
    scan2_kernel<<<1, 256, 0, stream>>>(blk_sums, nscan);
    scan3_kernel<<<(N + 1 + 255) / 256, 256, 0, stream>>>(row_start, rss, blk_sums, N);

    int T = (((E + EK - 1) / EK) + 255) & ~255;
    fill_kernel<<<T / 256, 256, 0, stream>>>(src, dst, rss, rank, csr_src, E, T, N);

    {
        long long threads = (long long)N * 64;
        gather1_kernel<<<(int)((threads + 255) / 256), 256, 0, stream>>>(
            xbf, row_start, csr_src, aggm, N);
    }
    int gblocks = (N + 63) / 64;
    mgemm1_kernel<<<gblocks, 256, 0, stream>>>(aggm, xbf, Bp1, b1, h1, N);
    mgemm2_kernel<<<gblocks, 256, 0, stream>>>(h1, Bp2, b2, zb, rbuf, N);
    {
        long long threads = (long long)N * 16;
        gather2_kernel<<<(int)((threads + 255) / 256), 256, 0, stream>>>(
            (const uint2*)zb, rbuf, row_start, csr_src, out, N);
    }
}

// Round 9
// 247.898 us; speedup vs baseline: 1.2859x; 1.2859x over previous
//
#include <hip/hip_runtime.h>
#include <math.h>

#define IN_FEATS 128
#define HIDDEN   256
#define CLASSES  41
#define CPAD     64
#define SCAN_BLK 1024
#define LDA      264    // 256 + 8 pad (bf16 elems)
#define CHUNK    8192   // edges per block in passA/passB
#define BSH      7      // bucket = dst >> 7 (128 nodes per bucket)
#define NBMAX    1024   // max buckets (N <= 131072)

typedef __attribute__((ext_vector_type(8))) short short8;
typedef __attribute__((ext_vector_type(4))) float f32x4;

__device__ __forceinline__ unsigned short f2bf(float f) {
    union { float f; unsigned u; } v; v.f = f;
    unsigned r = v.u + 0x7FFF + ((v.u >> 16) & 1);
    return (unsigned short)(r >> 16);
}
__device__ __forceinline__ float bf2f(unsigned short h) {
    union { unsigned u; float f; } v; v.u = ((unsigned)h) << 16;
    return v.f;
}

// ---- passA: per-chunk LDS histogram over buckets -> mat[b*NBLK + blk] ------
__global__ void __launch_bounds__(256)
passA_kernel(const int* __restrict__ dst, int* __restrict__ mat,
             int E, int NB, int NBLK) {
    __shared__ int hist[NBMAX];
    int blk = blockIdx.x, t = threadIdx.x;
    for (int b = t; b < NB; b += 256) hist[b] = 0;
    __syncthreads();
    int e0 = blk * CHUNK;
    for (int i = t; i < CHUNK; i += 256) {
        int e = e0 + i;
        if (e < E) atomicAdd(&hist[dst[e] >> BSH], 1);
    }
    __syncthreads();
    for (int b = t; b < NB; b += 256) mat[b * NBLK + blk] = hist[b];
}

// ---- scanM: in-place exclusive scan of mat[0..L], sentinel at L ------------
__global__ void __launch_bounds__(256)
scanM1_kernel(int* __restrict__ a, int* __restrict__ bs, int L) {
    __shared__ int lds[256];
    int base = blockIdx.x * SCAN_BLK;
    int t = threadIdx.x;
    int v[4];
    int s = 0;
#pragma unroll
    for (int i = 0; i < 4; ++i) {
        int idx = base + t * 4 + i;
        v[i] = (idx < L) ? a[idx] : 0;
        s += v[i];
    }
    lds[t] = s;
    __syncthreads();
    for (int off = 1; off < 256; off <<= 1) {
        int val = lds[t];
        int add = (t >= off) ? lds[t - off] : 0;
        __syncthreads();
        lds[t] = val + add;
        __syncthreads();
    }
    if (t == 255) bs[blockIdx.x] = lds[255];
    int run = (t == 0) ? 0 : lds[t - 1];
#pragma unroll
    for (int i = 0; i < 4; ++i) {
        int idx = base + t * 4 + i;
        if (idx <= L) a[idx] = run;
        run += v[i];
    }
}

__global__ void __launch_bounds__(256)
scan2_kernel(int* __restrict__ bs, int nb) {
    __shared__ int lds[256];
    int t = threadIdx.x;
    lds[t] = (t < nb) ? bs[t] : 0;
    __syncthreads();
    for (int off = 1; off < 256; off <<= 1) {
        int val = lds[t];
        int add = (t >= off) ? lds[t - off] : 0;
        __syncthreads();
        lds[t] = val + add;
        __syncthreads();
    }
    if (t < nb) bs[t] = (t == 0) ? 0 : lds[t - 1];
}

__global__ void __launch_bounds__(256)
scanM3_kernel(int* __restrict__ a, const int* __restrict__ bs, int L) {
    int idx = blockIdx.x * 256 + threadIdx.x;
    if (idx <= L) a[idx] += bs[idx / SCAN_BLK];
}

// ---- passB: scatter packed (src<<7 | dst&127) to bucket-major tmp ----------
__global__ void __launch_bounds__(256)
passB_kernel(const int* __restrict__ src, const int* __restrict__ dst,
             const int* __restrict__ mat, unsigned* __restrict__ tmp,
             int E, int NB, int NBLK) {
    __shared__ int cursor[NBMAX];
    int blk = blockIdx.x, t = threadIdx.x;
    for (int b = t; b < NB; b += 256) cursor[b] = mat[b * NBLK + blk];
    __syncthreads();
    int e0 = blk * CHUNK;
    for (int i = t; i < CHUNK; i += 256) {
        int e = e0 + i;
        if (e < E) {
            int d = dst[e], s = src[e];
            int b = d >> BSH;
            int pos = atomicAdd(&cursor[b], 1);
            tmp[pos] = (unsigned)((s << BSH) | (d & 127));
        }
    }
}

// ---- passC: per-bucket fine CSR: row_start + csr_src -----------------------
__global__ void __launch_bounds__(256)
passC_kernel(const unsigned* __restrict__ tmp, const int* __restrict__ mat,
             int* __restrict__ row_start, int* __restrict__ csr_src,
             int E, int N, int NB, int NBLK) {
    __shared__ int h[128], cur[128], sc[128];
    int b = blockIdx.x, t = threadIdx.x;
    int segBase = mat[b * NBLK];
    int segEnd  = mat[(b + 1) * NBLK];   // b=NB-1 -> mat[L] = E sentinel
    int len = segEnd - segBase;
    if (t < 128) h[t] = 0;
    __syncthreads();
    for (int i = t; i < len; i += 256)
        atomicAdd(&h[tmp[segBase + i] & 127], 1);
    __syncthreads();
    if (t < 128) sc[t] = h[t];
    __syncthreads();
    for (int off = 1; off < 128; off <<= 1) {
        int v2 = 0;
        if (t < 128) { v2 = sc[t]; if (t >= off) v2 += sc[t - off]; }
        __syncthreads();
        if (t < 128) sc[t] = v2;
        __syncthreads();
    }
    if (t < 128) {
        int base = segBase + sc[t] - h[t];   // exclusive
        cur[t] = base;
        int n = (b << BSH) + t;
        if (n < N) row_start[n] = base;
    }
    if (b == NB - 1 && t == 0) row_start[N] = segEnd;
    __syncthreads();
    for (int i = t; i < len; i += 256) {
        unsigned w = tmp[segBase + i];
        int pos = atomicAdd(&cur[w & 127], 1);
        csr_src[pos] = (int)(w >> BSH);
    }
}

// ---------------- xbf: x -> bf16 --------------------------------------------
__global__ void __launch_bounds__(256)
xbf_kernel(const float* __restrict__ x, unsigned short* __restrict__ xbf, long n4) {
    long i = (long)blockIdx.x * 256 + threadIdx.x;
    if (i >= n4) return;
    float4 v = *(const float4*)(x + i * 4);
    ushort4 o;
    o.x = f2bf(v.x); o.y = f2bf(v.y); o.z = f2bf(v.z); o.w = f2bf(v.w);
    *(ushort4*)(xbf + i * 4) = o;
}

// ------- prep: pack [W1l;W1r] -> Bp1 (256x256) and [W2l|W2r] -> Bp2 (256x96) -
__global__ void __launch_bounds__(256)
prep_kernel(const float* __restrict__ W1l, const float* __restrict__ W1r,
            const float* __restrict__ W2l, const float* __restrict__ W2r,
            unsigned short* __restrict__ Bp1, unsigned short* __restrict__ Bp2) {
    int idx = blockIdx.x * 256 + threadIdx.x;
    if (idx < 256 * 256) {
        int k = idx >> 8, c = idx & 255;
        float v = (k < 128) ? W1l[k * 256 + c] : W1r[(k - 128) * 256 + c];
        Bp1[((k >> 5) * 256 + c) * 32 + ((k & 31) >> 3) * 8 + (k & 7)] = f2bf(v);
    } else {
        int j = idx - 65536;
        if (j < 256 * 96) {
            int k = j / 96, c = j % 96;
            float v = 0.0f;
            if (c < 41) v = W2l[k * 41 + c];
            else if (c >= 48 && c < 89) v = W2r[k * 41 + (c - 48)];
            Bp2[((k >> 5) * 96 + c) * 32 + ((k & 31) >> 3) * 8 + (k & 7)] = f2bf(v);
        }
    }
}

// ------- gather1: aggm_bf[n] = bf16(mean_{s} xbf[s]), unroll-8 MLP ----------
__global__ void __launch_bounds__(256)
gather1_kernel(const unsigned short* __restrict__ xbf,
               const int* __restrict__ row_start,
               const int* __restrict__ csr_src, unsigned short* __restrict__ aggm,
               int N) {
    int wid = (blockIdx.x * 256 + threadIdx.x) >> 6;
    int lane = threadIdx.x & 63;
    if (wid >= N) return;
    int rs = row_start[wid];
    int d = row_start[wid + 1] - rs;
    const unsigned* xp = (const unsigned*)xbf;
    float sl[8], sh[8];
#pragma unroll
    for (int j = 0; j < 8; ++j) { sl[j] = 0.f; sh[j] = 0.f; }
    int i = 0;
    for (; i + 8 <= d; i += 8) {
        int s[8];
#pragma unroll
        for (int j = 0; j < 8; ++j) s[j] = csr_src[rs + i + j];
        unsigned u[8];
#pragma unroll
        for (int j = 0; j < 8; ++j) u[j] = xp[(size_t)s[j] * 64 + lane];
#pragma unroll
        for (int j = 0; j < 8; ++j) {
            sl[j] += bf2f((unsigned short)u[j]);
            sh[j] += bf2f((unsigned short)(u[j] >> 16));
        }
    }
    for (; i + 4 <= d; i += 4) {
        int s[4];
#pragma unroll
        for (int j = 0; j < 4; ++j) s[j] = csr_src[rs + i + j];
        unsigned u[4];
#pragma unroll
        for (int j = 0; j < 4; ++j) u[j] = xp[(size_t)s[j] * 64 + lane];
#pragma unroll
        for (int j = 0; j < 4; ++j) {
            sl[j] += bf2f((unsigned short)u[j]);
            sh[j] += bf2f((unsigned short)(u[j] >> 16));
        }
    }
    for (; i < d; ++i) {
        unsigned u0 = xp[(size_t)csr_src[rs + i] * 64 + lane];
        sl[0] += bf2f((unsigned short)u0);
        sh[0] += bf2f((unsigned short)(u0 >> 16));
    }
    float ax = ((sl[0] + sl[1]) + (sl[2] + sl[3])) + ((sl[4] + sl[5]) + (sl[6] + sl[7]));
    float ay = ((sh[0] + sh[1]) + (sh[2] + sh[3])) + ((sh[4] + sh[5]) + (sh[6] + sh[7]));
    float inv = 1.0f / fmaxf((float)d, 1.0f);
    unsigned o = ((unsigned)f2bf(ay * inv) << 16) | (unsigned)f2bf(ax * inv);
    ((unsigned*)aggm)[(size_t)wid * 64 + lane] = o;
}

// ---- fused mgemm: h1 = relu([aggm|xbf]@Bp1+b1) kept in LDS;
//      then zb = bf16(h1@W2l), rbuf = h1@W2r + b2 ----------------------------
__global__ void __launch_bounds__(256)
mgemm_fused_kernel(const unsigned short* __restrict__ aggm,
                   const unsigned short* __restrict__ xbf,
                   const unsigned short* __restrict__ Bp1, const float* __restrict__ b1,
                   const unsigned short* __restrict__ Bp2, const float* __restrict__ b2,
                   unsigned short* __restrict__ zb, float* __restrict__ rbuf, int N) {
    __shared__ __align__(16) unsigned short alds[64 * LDA];
    int n0 = blockIdx.x * 64;
    int t = threadIdx.x;
#pragma unroll
    for (int i = 0; i < 8; ++i) {
        int cid = t + i * 256;
        int row = cid >> 5, c16 = cid & 31;
        int gr = n0 + row;
        uint4 v = make_uint4(0, 0, 0, 0);
        if (gr < N) {
            const unsigned short* srcp = (c16 < 16)
                ? (aggm + (size_t)gr * 128 + c16 * 8)
                : (xbf  + (size_t)gr * 128 + (c16 - 16) * 8);
            v = *(const uint4*)srcp;
        }
        *(uint4*)&alds[row * LDA + c16 * 8] = v;
    }
    __syncthreads();
    int wid = t >> 6, lane = t & 63;
    int l15 = lane & 15, g = lane >> 4;
    int col0 = wid * 64;
    f32x4 acc[4][4];
#pragma unroll
    for (int mf = 0; mf < 4; ++mf)
#pragma unroll
        for (int nf = 0; nf < 4; ++nf) acc[mf][nf] = (f32x4)(0.0f);
    for (int ks = 0; ks < 8; ++ks) {
        short8 af[4], bfr[4];
#pragma unroll
        for (int mf = 0; mf < 4; ++mf)
            af[mf] = *(const short8*)&alds[(mf * 16 + l15) * LDA + ks * 32 + g * 8];
#pragma unroll
        for (int nf = 0; nf < 4; ++nf)
            bfr[nf] = *(const short8*)&Bp1[((size_t)ks * 256 + col0 + nf * 16 + l15) * 32 + g * 8];
#pragma unroll
        for (int mf = 0; mf < 4; ++mf)
#pragma unroll
            for (int nf = 0; nf < 4; ++nf)
                acc[mf][nf] = __builtin_amdgcn_mfma_f32_16x16x32_bf16(
                    af[mf], bfr[nf], acc[mf][nf], 0, 0, 0);
    }
    float bc[4];
#pragma unroll
    for (int nf = 0; nf < 4; ++nf) bc[nf] = b1[col0 + nf * 16 + l15];
    __syncthreads();   // all alds reads done; reuse alds for h1 tile
#pragma unroll
    for (int mf = 0; mf < 4; ++mf) {
#pragma unroll
        for (int r = 0; r < 4; ++r) {
            int row = mf * 16 + g * 4 + r;
#pragma unroll
            for (int nf = 0; nf < 4; ++nf)
                alds[row * LDA + col0 + nf * 16 + l15] =
                    f2bf(fmaxf(acc[mf][nf][r] + bc[nf], 0.0f));
        }
    }
    __syncthreads();
    // ---- phase 2: zb/rbuf from LDS h1 tile ----
    int wr = wid >> 1, wc = wid & 1;
    f32x4 acc2[2][3];
#pragma unroll
    for (int mf = 0; mf < 2; ++mf)
#pragma unroll
        for (int nf = 0; nf < 3; ++nf) acc2[mf][nf] = (f32x4)(0.0f);
    for (int ks = 0; ks < 8; ++ks) {
        short8 af[2], bfr[3];
#pragma unroll
        for (int mf = 0; mf < 2; ++mf)
            af[mf] = *(const short8*)&alds[(wr * 32 + mf * 16 + l15) * LDA + ks * 32 + g * 8];
#pragma unroll
        for (int nf = 0; nf < 3; ++nf)
            bfr[nf] = *(const short8*)&Bp2[((size_t)ks * 96 + wc * 48 + nf * 16 + l15) * 32 + g * 8];
#pragma unroll
        for (int mf = 0; mf < 2; ++mf)
#pragma unroll
            for (int nf = 0; nf < 3; ++nf)
                acc2[mf][nf] = __builtin_amdgcn_mfma_f32_16x16x32_bf16(
                    af[mf], bfr[nf], acc2[mf][nf], 0, 0, 0);
    }
#pragma unroll
    for (int nf = 0; nf < 3; ++nf) {
        int col = wc * 48 + nf * 16 + l15;
        float bb = (col >= 48 && col < 89) ? b2[col - 48] : 0.0f;
#pragma unroll
        for (int mf = 0; mf < 2; ++mf) {
            int rowb = n0 + wr * 32 + mf * 16 + g * 4;
#pragma unroll
            for (int r = 0; r < 4; ++r) {
                int row = rowb + r;
                if (row < N) {
                    float v = acc2[mf][nf][r];
                    if (col < 41)                   zb[(size_t)row * CPAD + col] = f2bf(v);
                    else if (col >= 48 && col < 89) rbuf[(size_t)row * CPAD + (col - 48)] = v + bb;
                }
            }
        }
    }
}

// -- gather2+final: 4 nodes/wave (16 lanes each, uint2 = 4 classes), unroll-4
__global__ void __launch_bounds__(256)
gather2_kernel(const uint2* __restrict__ zp, const float* __restrict__ rbuf,
               const int* __restrict__ row_start,
               const int* __restrict__ csr_src, float* __restrict__ out, int N) {
    int tid = blockIdx.x * 256 + threadIdx.x;
    int nid = tid >> 4;
    int l = tid & 15;
    if (nid >= N) return;
    int rs = row_start[nid];
    int d = row_start[nid + 1] - rs;
    float a[4][4];
#pragma unroll
    for (int j = 0; j < 4; ++j)
#pragma unroll
        for (int k = 0; k < 4; ++k) a[j][k] = 0.f;
    int i = 0;
    for (; i + 4 <= d; i += 4) {
        int s[4];
#pragma unroll
        for (int j = 0; j < 4; ++j) s[j] = csr_src[rs + i + j];
        uint2 u[4];
#pragma unroll
        for (int j = 0; j < 4; ++j) u[j] = zp[(size_t)s[j] * 16 + l];
#pragma unroll
        for (int j = 0; j < 4; ++j) {
            a[j][0] += bf2f((unsigned short)u[j].x);
            a[j][1] += bf2f((unsigned short)(u[j].x >> 16));
            a[j][2] += bf2f((unsigned short)u[j].y);
            a[j][3] += bf2f((unsigned short)(u[j].y >> 16));
        }
    }
    for (; i < d; ++i) {
        uint2 u0 = zp[(size_t)csr_src[rs + i] * 16 + l];
        a[0][0] += bf2f((unsigned short)u0.x);
        a[0][1] += bf2f((unsigned short)(u0.x >> 16));
        a[0][2] += bf2f((unsigned short)u0.y);
        a[0][3] += bf2f((unsigned short)(u0.y >> 16));
    }
    float inv = 1.0f / fmaxf((float)d, 1.0f);
    float4 rb = *(const float4*)&rbuf[(size_t)nid * CPAD + 4 * l];
    float rbv[4] = {rb.x, rb.y, rb.z, rb.w};
    float v[4];
#pragma unroll
    for (int k = 0; k < 4; ++k) {
        int col = 4 * l + k;
        v[k] = (col < CLASSES)
             ? ((a[0][k] + a[1][k]) + (a[2][k] + a[3][k])) * inv + rbv[k]
             : -INFINITY;
    }
    float m = fmaxf(fmaxf(v[0], v[1]), fmaxf(v[2], v[3]));
#pragma unroll
    for (int off = 8; off; off >>= 1) m = fmaxf(m, __shfl_xor(m, off, 16));
    float s = 0.f;
#pragma unroll
    for (int k = 0; k < 4; ++k)
        s += (4 * l + k < CLASSES) ? expf(v[k] - m) : 0.0f;
#pragma unroll
    for (int off = 8; off; off >>= 1) s += __shfl_xor(s, off, 16);
    float lse = m + logf(s);
#pragma unroll
    for (int k = 0; k < 4; ++k) {
        int col = 4 * l + k;
        if (col < CLASSES) out[(size_t)nid * CLASSES + col] = v[k] - lse;
    }
}

extern "C" void kernel_launch(void* const* d_in, const int* in_sizes, int n_in,
                              void* d_out, int out_size, void* d_ws, size_t ws_size,
                              hipStream_t stream) {
    const float* x   = (const float*)d_in[0];
    const int*   ei  = (const int*)d_in[1];
    const float* W1l = (const float*)d_in[2];
    const float* W1r = (const float*)d_in[3];
    const float* b1  = (const float*)d_in[4];
    const float* W2l = (const float*)d_in[5];
    const float* W2r = (const float*)d_in[6];
    const float* b2  = (const float*)d_in[7];
    float* out = (float*)d_out;

    int N = in_sizes[0] / IN_FEATS;
    int E = in_sizes[1] / 2;
    const int* src = ei;
    const int* dst = ei + E;

    int NB   = (N + 127) >> BSH;                 // buckets (782)
    int NBLK = (E + CHUNK - 1) / CHUNK;          // chunks (196)
    int L    = NB * NBLK;

    // ints: [mat L+1][blk_sums 256][row_start N+1][tmp E (u32)][csr_src E]
    int* ws_i      = (int*)d_ws;
    int* mat       = ws_i;
    int* blk_sums  = ws_i + (size_t)L + 1;
    int* row_start = blk_sums + 256;
    unsigned* tmp  = (unsigned*)(row_start + (size_t)N + 1);
    int* csr_src   = (int*)(tmp + (size_t)E);
    size_t int_bytes = ((size_t)L + 1 + 256 + (size_t)N + 1 + 2 * (size_t)E) * sizeof(int);
    char* p = (char*)d_ws + ((int_bytes + 15) & ~(size_t)15);
    unsigned short* xbf  = (unsigned short*)p;            p += (size_t)N * 128 * 2;
    unsigned short* aggm = (unsigned short*)p;            p += (size_t)N * 128 * 2;
    unsigned short* Bp1  = (unsigned short*)p;            p += 65536 * 2;
    unsigned short* Bp2  = (unsigned short*)p;            p += 24576 * 2;
    unsigned short* zb   = (unsigned short*)p;            p += (size_t)N * CPAD * 2;
    float* rbuf = (float*)p;

    // ---- CSR construction (atomic-free wrt global memory) ----
    passA_kernel<<<NBLK, 256, 0, stream>>>(dst, mat, E, NB, NBLK);
    int nscanM = (L + 1 + SCAN_BLK - 1) / SCAN_BLK;
    scanM1_kernel<<<nscanM, 256, 0, stream>>>(mat, blk_sums, L);
    scan2_kernel<<<1, 256, 0, stream>>>(blk_sums, nscanM);
    scanM3_kernel<<<(L + 1 + 255) / 256, 256, 0, stream>>>(mat, blk_sums, L);
    passB_kernel<<<NBLK, 256, 0, stream>>>(src, dst, mat, tmp, E, NB, NBLK);
    passC_kernel<<<NB, 256, 0, stream>>>(tmp, mat, row_start, csr_src, E, N, NB, NBLK);

    // ---- weights + x conversion (xbf last: keep it warm for gather1) ----
    prep_kernel<<<(65536 + 24576 + 255) / 256, 256, 0, stream>>>(
        W1l, W1r, W2l, W2r, Bp1, Bp2);
    long n4 = (long)N * 128 / 4;
    xbf_kernel<<<(int)((n4 + 255) / 256), 256, 0, stream>>>(x, xbf, n4);

    {
        long long threads = (long long)N * 64;
        gather1_kernel<<<(int)((threads + 255) / 256), 256, 0, stream>>>(
            xbf, row_start, csr_src, aggm, N);
    }
    int gblocks = (N + 63) / 64;
    mgemm_fused_kernel<<<gblocks, 256, 0, stream>>>(aggm, xbf, Bp1, b1,
                                                    Bp2, b2, zb, rbuf, N);
    {
        long long threads = (long long)N * 16;
        gather2_kernel<<<(int)((threads + 255) / 256), 256, 0, stream>>>(
            (const uint2*)zb, rbuf, row_start, csr_src, out, N);
    }
}

// Round 10
// 213.344 us; speedup vs baseline: 1.4942x; 1.1620x over previous
//
#include <hip/hip_runtime.h>
#include <math.h>

#define IN_FEATS 128
#define HIDDEN   256
#define CLASSES  41
#define CPAD     64
#define SCAN_BLK 1024
#define LDA      264    // 256 + 8 pad (bf16 elems)
#define CHUNK    8192   // edges per block in passA/passB
#define BSH      7      // bucket = dst >> 7 (128 nodes per bucket)
#define NBMAX    1024   // max buckets (N <= 131072)

typedef __attribute__((ext_vector_type(8))) short short8;
typedef __attribute__((ext_vector_type(4))) float f32x4;
typedef __attribute__((ext_vector_type(2))) float f32x2;

__device__ __forceinline__ unsigned short f2bf(float f) {
    union { float f; unsigned u; } v; v.f = f;
    unsigned r = v.u + 0x7FFF + ((v.u >> 16) & 1);
    return (unsigned short)(r >> 16);
}
__device__ __forceinline__ float bf2f(unsigned short h) {
    union { unsigned u; float f; } v; v.u = ((unsigned)h) << 16;
    return v.f;
}

// ---- passA: per-chunk LDS histogram over buckets -> mat[b*NBLK + blk] ------
__global__ void __launch_bounds__(256)
passA_kernel(const int* __restrict__ dst, int* __restrict__ mat,
             int E, int NB, int NBLK) {
    __shared__ int hist[NBMAX];
    int blk = blockIdx.x, t = threadIdx.x;
    for (int b = t; b < NB; b += 256) hist[b] = 0;
    __syncthreads();
    int e0 = blk * CHUNK;
    for (int i = t; i < CHUNK; i += 256) {
        int e = e0 + i;
        if (e < E) atomicAdd(&hist[dst[e] >> BSH], 1);
    }
    __syncthreads();
    for (int b = t; b < NB; b += 256) mat[b * NBLK + blk] = hist[b];
}

// ---- scanM: in-place exclusive scan of mat[0..L], sentinel at L ------------
__global__ void __launch_bounds__(256)
scanM1_kernel(int* __restrict__ a, int* __restrict__ bs, int L) {
    __shared__ int lds[256];
    int base = blockIdx.x * SCAN_BLK;
    int t = threadIdx.x;
    int v[4];
    int s = 0;
#pragma unroll
    for (int i = 0; i < 4; ++i) {
        int idx = base + t * 4 + i;
        v[i] = (idx < L) ? a[idx] : 0;
        s += v[i];
    }
    lds[t] = s;
    __syncthreads();
    for (int off = 1; off < 256; off <<= 1) {
        int val = lds[t];
        int add = (t >= off) ? lds[t - off] : 0;
        __syncthreads();
        lds[t] = val + add;
        __syncthreads();
    }
    if (t == 255) bs[blockIdx.x] = lds[255];
    int run = (t == 0) ? 0 : lds[t - 1];
#pragma unroll
    for (int i = 0; i < 4; ++i) {
        int idx = base + t * 4 + i;
        if (idx <= L) a[idx] = run;
        run += v[i];
    }
}

__global__ void __launch_bounds__(256)
scan2_kernel(int* __restrict__ bs, int nb) {
    __shared__ int lds[256];
    int t = threadIdx.x;
    lds[t] = (t < nb) ? bs[t] : 0;
    __syncthreads();
    for (int off = 1; off < 256; off <<= 1) {
        int val = lds[t];
        int add = (t >= off) ? lds[t - off] : 0;
        __syncthreads();
        lds[t] = val + add;
        __syncthreads();
    }
    if (t < nb) bs[t] = (t == 0) ? 0 : lds[t - 1];
}

__global__ void __launch_bounds__(256)
scanM3_kernel(int* __restrict__ a, const int* __restrict__ bs, int L) {
    int idx = blockIdx.x * 256 + threadIdx.x;
    if (idx <= L) a[idx] += bs[idx / SCAN_BLK];
}

// ---- passB: scatter packed (src<<7 | dst&127) to bucket-major tmp ----------
__global__ void __launch_bounds__(256)
passB_kernel(const int* __restrict__ src, const int* __restrict__ dst,
             const int* __restrict__ mat, unsigned* __restrict__ tmp,
             int E, int NB, int NBLK) {
    __shared__ int cursor[NBMAX];
    int blk = blockIdx.x, t = threadIdx.x;
    for (int b = t; b < NB; b += 256) cursor[b] = mat[b * NBLK + blk];
    __syncthreads();
    int e0 = blk * CHUNK;
    for (int i = t; i < CHUNK; i += 256) {
        int e = e0 + i;
        if (e < E) {
            int d = dst[e], s = src[e];
            int b = d >> BSH;
            int pos = atomicAdd(&cursor[b], 1);
            tmp[pos] = (unsigned)((s << BSH) | (d & 127));
        }
    }
}

// ---- passC: per-bucket fine CSR: row_start + csr_src -----------------------
__global__ void __launch_bounds__(256)
passC_kernel(const unsigned* __restrict__ tmp, const int* __restrict__ mat,
             int* __restrict__ row_start, int* __restrict__ csr_src,
             int E, int N, int NB, int NBLK) {
    __shared__ int h[128], cur[128], sc[128];
    int b = blockIdx.x, t = threadIdx.x;
    int segBase = mat[b * NBLK];
    int segEnd  = mat[(b + 1) * NBLK];
    int len = segEnd - segBase;
    if (t < 128) h[t] = 0;
    __syncthreads();
    for (int i = t; i < len; i += 256)
        atomicAdd(&h[tmp[segBase + i] & 127], 1);
    __syncthreads();
    if (t < 128) sc[t] = h[t];
    __syncthreads();
    for (int off = 1; off < 128; off <<= 1) {
        int v2 = 0;
        if (t < 128) { v2 = sc[t]; if (t >= off) v2 += sc[t - off]; }
        __syncthreads();
        if (t < 128) sc[t] = v2;
        __syncthreads();
    }
    if (t < 128) {
        int base = segBase + sc[t] - h[t];
        cur[t] = base;
        int n = (b << BSH) + t;
        if (n < N) row_start[n] = base;
    }
    if (b == NB - 1 && t == 0) row_start[N] = segEnd;
    __syncthreads();
    for (int i = t; i < len; i += 256) {
        unsigned w = tmp[segBase + i];
        int pos = atomicAdd(&cur[w & 127], 1);
        csr_src[pos] = (int)(w >> BSH);
    }
}

// ---- xcvt: x -> bf16 (xbf) + fp8 e4m3 (xf8) --------------------------------
__global__ void __launch_bounds__(256)
xcvt_kernel(const float* __restrict__ x, unsigned short* __restrict__ xbf,
            unsigned* __restrict__ xf8, long n4) {
    long i = (long)blockIdx.x * 256 + threadIdx.x;
    if (i >= n4) return;
    float4 v = *(const float4*)(x + i * 4);
    ushort4 o;
    o.x = f2bf(v.x); o.y = f2bf(v.y); o.z = f2bf(v.z); o.w = f2bf(v.w);
    *(ushort4*)(xbf + i * 4) = o;
    unsigned u = __builtin_amdgcn_cvt_pk_fp8_f32(v.x, v.y, 0, false);
    u = __builtin_amdgcn_cvt_pk_fp8_f32(v.z, v.w, u, true);
    xf8[i] = u;
}

// ------- prep: pack [W1l;W1r] -> Bp1 (256x256) and [W2l|W2r] -> Bp2 (256x96) -
__global__ void __launch_bounds__(256)
prep_kernel(const float* __restrict__ W1l, const float* __restrict__ W1r,
            const float* __restrict__ W2l, const float* __restrict__ W2r,
            unsigned short* __restrict__ Bp1, unsigned short* __restrict__ Bp2) {
    int idx = blockIdx.x * 256 + threadIdx.x;
    if (idx < 256 * 256) {
        int k = idx >> 8, c = idx & 255;
        float v = (k < 128) ? W1l[k * 256 + c] : W1r[(k - 128) * 256 + c];
        Bp1[((k >> 5) * 256 + c) * 32 + ((k & 31) >> 3) * 8 + (k & 7)] = f2bf(v);
    } else {
        int j = idx - 65536;
        if (j < 256 * 96) {
            int k = j / 96, c = j % 96;
            float v = 0.0f;
            if (c < 41) v = W2l[k * 41 + c];
            else if (c >= 48 && c < 89) v = W2r[k * 41 + (c - 48)];
            Bp2[((k >> 5) * 96 + c) * 32 + ((k & 31) >> 3) * 8 + (k & 7)] = f2bf(v);
        }
    }
}

// ------- gather1: aggm_bf[n] = bf16(mean_{s} xf8[s]), unroll-8 MLP ----------
__global__ void __launch_bounds__(256)
gather1_kernel(const unsigned short* __restrict__ xf8,
               const int* __restrict__ row_start,
               const int* __restrict__ csr_src, unsigned short* __restrict__ aggm,
               int N) {
    int wid = (blockIdx.x * 256 + threadIdx.x) >> 6;
    int lane = threadIdx.x & 63;
    if (wid >= N) return;
    int rs = row_start[wid];
    int d = row_start[wid + 1] - rs;
    float sl[8], sh[8];
#pragma unroll
    for (int j = 0; j < 8; ++j) { sl[j] = 0.f; sh[j] = 0.f; }
    int i = 0;
    for (; i + 8 <= d; i += 8) {
        int s[8];
#pragma unroll
        for (int j = 0; j < 8; ++j) s[j] = csr_src[rs + i + j];
        unsigned short u[8];
#pragma unroll
        for (int j = 0; j < 8; ++j) u[j] = xf8[(size_t)s[j] * 64 + lane];
#pragma unroll
        for (int j = 0; j < 8; ++j) {
            f32x2 f = __builtin_amdgcn_cvt_pk_f32_fp8((int)u[j], false);
            sl[j] += f.x; sh[j] += f.y;
        }
    }
    for (; i + 4 <= d; i += 4) {
        int s[4];
#pragma unroll
        for (int j = 0; j < 4; ++j) s[j] = csr_src[rs + i + j];
        unsigned short u[4];
#pragma unroll
        for (int j = 0; j < 4; ++j) u[j] = xf8[(size_t)s[j] * 64 + lane];
#pragma unroll
        for (int j = 0; j < 4; ++j) {
            f32x2 f = __builtin_amdgcn_cvt_pk_f32_fp8((int)u[j], false);
            sl[j] += f.x; sh[j] += f.y;
        }
    }
    for (; i < d; ++i) {
        unsigned short u0 = xf8[(size_t)csr_src[rs + i] * 64 + lane];
        f32x2 f = __builtin_amdgcn_cvt_pk_f32_fp8((int)u0, false);
        sl[0] += f.x; sh[0] += f.y;
    }
    float ax = ((sl[0] + sl[1]) + (sl[2] + sl[3])) + ((sl[4] + sl[5]) + (sl[6] + sl[7]));
    float ay = ((sh[0] + sh[1]) + (sh[2] + sh[3])) + ((sh[4] + sh[5]) + (sh[6] + sh[7]));
    float inv = 1.0f / fmaxf((float)d, 1.0f);
    unsigned o = ((unsigned)f2bf(ay * inv) << 16) | (unsigned)f2bf(ax * inv);
    ((unsigned*)aggm)[(size_t)wid * 64 + lane] = o;
}

// ---- fused mgemm: h1 = relu([aggm|xbf]@Bp1+b1) kept in LDS;
//      then zb8 = fp8(h1@W2l), rbuf = h1@W2r + b2 ----------------------------
__global__ void __launch_bounds__(256)
mgemm_fused_kernel(const unsigned short* __restrict__ aggm,
                   const unsigned short* __restrict__ xbf,
                   const unsigned short* __restrict__ Bp1, const float* __restrict__ b1,
                   const unsigned short* __restrict__ Bp2, const float* __restrict__ b2,
                   unsigned char* __restrict__ zb8, float* __restrict__ rbuf, int N) {
    __shared__ __align__(16) unsigned short alds[64 * LDA];
    int n0 = blockIdx.x * 64;
    int t = threadIdx.x;
#pragma unroll
    for (int i = 0; i < 8; ++i) {
        int cid = t + i * 256;
        int row = cid >> 5, c16 = cid & 31;
        int gr = n0 + row;
        uint4 v = make_uint4(0, 0, 0, 0);
        if (gr < N) {
            const unsigned short* srcp = (c16 < 16)
                ? (aggm + (size_t)gr * 128 + c16 * 8)
                : (xbf  + (size_t)gr * 128 + (c16 - 16) * 8);
            v = *(const uint4*)srcp;
        }
        *(uint4*)&alds[row * LDA + c16 * 8] = v;
    }
    __syncthreads();
    int wid = t >> 6, lane = t & 63;
    int l15 = lane & 15, g = lane >> 4;
    int col0 = wid * 64;
    f32x4 acc[4][4];
#pragma unroll
    for (int mf = 0; mf < 4; ++mf)
#pragma unroll
        for (int nf = 0; nf < 4; ++nf) acc[mf][nf] = (f32x4)(0.0f);
    for (int ks = 0; ks < 8; ++ks) {
        short8 af[4], bfr[4];
#pragma unroll
        for (int mf = 0; mf < 4; ++mf)
            af[mf] = *(const short8*)&alds[(mf * 16 + l15) * LDA + ks * 32 + g * 8];
#pragma unroll
        for (int nf = 0; nf < 4; ++nf)
            bfr[nf] = *(const short8*)&Bp1[((size_t)ks * 256 + col0 + nf * 16 + l15) * 32 + g * 8];
#pragma unroll
        for (int mf = 0; mf < 4; ++mf)
#pragma unroll
            for (int nf = 0; nf < 4; ++nf)
                acc[mf][nf] = __builtin_amdgcn_mfma_f32_16x16x32_bf16(
                    af[mf], bfr[nf], acc[mf][nf], 0, 0, 0);
    }
    float bc[4];
#pragma unroll
    for (int nf = 0; nf < 4; ++nf) bc[nf] = b1[col0 + nf * 16 + l15];
    __syncthreads();   // all alds reads done; reuse alds for h1 tile
#pragma unroll
    for (int mf = 0; mf < 4; ++mf) {
#pragma unroll
        for (int r = 0; r < 4; ++r) {
            int row = mf * 16 + g * 4 + r;
#pragma unroll
            for (int nf = 0; nf < 4; ++nf)
                alds[row * LDA + col0 + nf * 16 + l15] =
                    f2bf(fmaxf(acc[mf][nf][r] + bc[nf], 0.0f));
        }
    }
    __syncthreads();
    // ---- phase 2: zb8/rbuf from LDS h1 tile ----
    int wr = wid >> 1, wc = wid & 1;
    f32x4 acc2[2][3];
#pragma unroll
    for (int mf = 0; mf < 2; ++mf)
#pragma unroll
        for (int nf = 0; nf < 3; ++nf) acc2[mf][nf] = (f32x4)(0.0f);
    for (int ks = 0; ks < 8; ++ks) {
        short8 af[2], bfr[3];
#pragma unroll
        for (int mf = 0; mf < 2; ++mf)
            af[mf] = *(const short8*)&alds[(wr * 32 + mf * 16 + l15) * LDA + ks * 32 + g * 8];
#pragma unroll
        for (int nf = 0; nf < 3; ++nf)
            bfr[nf] = *(const short8*)&Bp2[((size_t)ks * 96 + wc * 48 + nf * 16 + l15) * 32 + g * 8];
#pragma unroll
        for (int mf = 0; mf < 2; ++mf)
#pragma unroll
            for (int nf = 0; nf < 3; ++nf)
                acc2[mf][nf] = __builtin_amdgcn_mfma_f32_16x16x32_bf16(
                    af[mf], bfr[nf], acc2[mf][nf], 0, 0, 0);
    }
#pragma unroll
    for (int nf = 0; nf < 3; ++nf) {
        int col = wc * 48 + nf * 16 + l15;
        float bb = (col >= 48 && col < 89) ? b2[col - 48] : 0.0f;
#pragma unroll
        for (int mf = 0; mf < 2; ++mf) {
            int rowb = n0 + wr * 32 + mf * 16 + g * 4;
#pragma unroll
            for (int r = 0; r < 4; ++r) {
                int row = rowb + r;
                if (row < N) {
                    float v = acc2[mf][nf][r];
                    if (col < 41) {
                        unsigned u = __builtin_amdgcn_cvt_pk_fp8_f32(v, 0.0f, 0, false);
                        zb8[(size_t)row * CPAD + col] = (unsigned char)(u & 0xff);
                    } else if (col >= 48 && col < 89) {
                        rbuf[(size_t)row * CPAD + (col - 48)] = v + bb;
                    }
                }
            }
        }
    }
}

// -- gather2+final: 4 nodes/wave (16 lanes each, uint = 4 fp8), unroll-4 -----
__global__ void __launch_bounds__(256)
gather2_kernel(const unsigned* __restrict__ zp8, const float* __restrict__ rbuf,
               const int* __restrict__ row_start,
               const int* __restrict__ csr_src, float* __restrict__ out, int N) {
    int tid = blockIdx.x * 256 + threadIdx.x;
    int nid = tid >> 4;
    int l = tid & 15;
    if (nid >= N) return;
    int rs = row_start[nid];
    int d = row_start[nid + 1] - rs;
    float a[4][4];
#pragma unroll
    for (int j = 0; j < 4; ++j)
#pragma unroll
        for (int k = 0; k < 4; ++k) a[j][k] = 0.f;
    int i = 0;
    for (; i + 4 <= d; i += 4) {
        int s[4];
#pragma unroll
        for (int j = 0; j < 4; ++j) s[j] = csr_src[rs + i + j];
        unsigned u[4];
#pragma unroll
        for (int j = 0; j < 4; ++j) u[j] = zp8[(size_t)s[j] * 16 + l];
#pragma unroll
        for (int j = 0; j < 4; ++j) {
            f32x2 lo = __builtin_amdgcn_cvt_pk_f32_fp8((int)u[j], false);
            f32x2 hi = __builtin_amdgcn_cvt_pk_f32_fp8((int)u[j], true);
            a[j][0] += lo.x; a[j][1] += lo.y; a[j][2] += hi.x; a[j][3] += hi.y;
        }
    }
    for (; i < d; ++i) {
        unsigned u0 = zp8[(size_t)csr_src[rs + i] * 16 + l];
        f32x2 lo = __builtin_amdgcn_cvt_pk_f32_fp8((int)u0, false);
        f32x2 hi = __builtin_amdgcn_cvt_pk_f32_fp8((int)u0, true);
        a[0][0] += lo.x; a[0][1] += lo.y; a[0][2] += hi.x; a[0][3] += hi.y;
    }
    float inv = 1.0f / fmaxf((float)d, 1.0f);
    float4 rb = *(const float4*)&rbuf[(size_t)nid * CPAD + 4 * l];
    float rbv[4] = {rb.x, rb.y, rb.z, rb.w};
    float v[4];
#pragma unroll
    for (int k = 0; k < 4; ++k) {
        int col = 4 * l + k;
        v[k] = (col < CLASSES)
             ? ((a[0][k] + a[1][k]) + (a[2][k] + a[3][k])) * inv + rbv[k]
             : -INFINITY;
    }
    float m = fmaxf(fmaxf(v[0], v[1]), fmaxf(v[2], v[3]));
#pragma unroll
    for (int off = 8; off; off >>= 1) m = fmaxf(m, __shfl_xor(m, off, 16));
    float s = 0.f;
#pragma unroll
    for (int k = 0; k < 4; ++k)
        s += (4 * l + k < CLASSES) ? expf(v[k] - m) : 0.0f;
#pragma unroll
    for (int off = 8; off; off >>= 1) s += __shfl_xor(s, off, 16);
    float lse = m + logf(s);
#pragma unroll
    for (int k = 0; k < 4; ++k) {
        int col = 4 * l + k;
        if (col < CLASSES) out[(size_t)nid * CLASSES + col] = v[k] - lse;
    }
}

extern "C" void kernel_launch(void* const* d_in, const int* in_sizes, int n_in,
                              void* d_out, int out_size, void* d_ws, size_t ws_size,
                              hipStream_t stream) {
    const float* x   = (const float*)d_in[0];
    const int*   ei  = (const int*)d_in[1];
    const float* W1l = (const float*)d_in[2];
    const float* W1r = (const float*)d_in[3];
    const float* b1  = (const float*)d_in[4];
    const float* W2l = (const float*)d_in[5];
    const float* W2r = (const float*)d_in[6];
    const float* b2  = (const float*)d_in[7];
    float* out = (float*)d_out;

    int N = in_sizes[0] / IN_FEATS;
    int E = in_sizes[1] / 2;
    const int* src = ei;
    const int* dst = ei + E;

    int NB   = (N + 127) >> BSH;
    int NBLK = (E + CHUNK - 1) / CHUNK;
    int L    = NB * NBLK;

    // ints: [mat L+1][blk_sums 256][row_start N+1][tmp E (u32)][csr_src E]
    int* ws_i      = (int*)d_ws;
    int* mat       = ws_i;
    int* blk_sums  = ws_i + (size_t)L + 1;
    int* row_start = blk_sums + 256;
    unsigned* tmp  = (unsigned*)(row_start + (size_t)N + 1);
    int* csr_src   = (int*)(tmp + (size_t)E);
    size_t int_bytes = ((size_t)L + 1 + 256 + (size_t)N + 1 + 2 * (size_t)E) * sizeof(int);
    char* p = (char*)d_ws + ((int_bytes + 15) & ~(size_t)15);
    unsigned short* xbf  = (unsigned short*)p;            p += (size_t)N * 128 * 2;
    unsigned*       xf8  = (unsigned*)p;                  p += (size_t)N * 128;
    unsigned short* aggm = (unsigned short*)p;            p += (size_t)N * 128 * 2;
    unsigned short* Bp1  = (unsigned short*)p;            p += 65536 * 2;
    unsigned short* Bp2  = (unsigned short*)p;            p += 24576 * 2;
    unsigned char*  zb8  = (unsigned char*)p;             p += (size_t)N * CPAD;
    float* rbuf = (float*)p;

    // ---- CSR construction (no global atomics) ----
    passA_kernel<<<NBLK, 256, 0, stream>>>(dst, mat, E, NB, NBLK);
    int nscanM = (L + 1 + SCAN_BLK - 1) / SCAN_BLK;
    scanM1_kernel<<<nscanM, 256, 0, stream>>>(mat, blk_sums, L);
    scan2_kernel<<<1, 256, 0, stream>>>(blk_sums, nscanM);
    scanM3_kernel<<<(L + 1 + 255) / 256, 256, 0, stream>>>(mat, blk_sums, L);
    passB_kernel<<<NBLK, 256, 0, stream>>>(src, dst, mat, tmp, E, NB, NBLK);
    passC_kernel<<<NB, 256, 0, stream>>>(tmp, mat, row_start, csr_src, E, N, NB, NBLK);

    // ---- weights + x conversion (xcvt last: keep xf8 warm for gather1) ----
    prep_kernel<<<(65536 + 24576 + 255) / 256, 256, 0, stream>>>(
        W1l, W1r, W2l, W2r, Bp1, Bp2);
    long n4 = (long)N * 128 / 4;
    xcvt_kernel<<<(int)((n4 + 255) / 256), 256, 0, stream>>>(x, xbf, xf8, n4);

    {
        long long threads = (long long)N * 64;
        gather1_kernel<<<(int)((threads + 255) / 256), 256, 0, stream>>>(
            (const unsigned short*)xf8, row_start, csr_src, aggm, N);
    }
    int gblocks = (N + 63) / 64;
    mgemm_fused_kernel<<<gblocks, 256, 0, stream>>>(aggm, xbf, Bp1, b1,
                                                    Bp2, b2, zb8, rbuf, N);
    {
        long long threads = (long long)N * 16;
        gather2_kernel<<<(int)((threads + 255) / 256), 256, 0, stream>>>(
            (const unsigned*)zb8, rbuf, row_start, csr_src, out, N);
    }
}